// Round 4
// baseline (306.964 us; speedup 1.0000x reference)
//
#include <hip/hip_runtime.h>
#include <stdint.h>

typedef __attribute__((ext_vector_type(8)))  short short8;   // 8 bf16 (4 VGPRs)
typedef __attribute__((ext_vector_type(4)))  float float4v;
typedef __attribute__((ext_vector_type(16))) float f32x16;   // 32x32 MFMA C/D

#define B_  16
#define S_  4096
#define D_  128
#define TM  128         // Q rows per block (QK: 4 waves x 32 rows)
#define TN  64          // keys per tile
#define NT_ (S_ / TN)   // 64 key-tiles per batch
#define IMG 8192        // shorts per 64x128 tile image (16 KB)

// fp32 -> bf16 round-to-nearest-even
__device__ __forceinline__ unsigned short f2bf(float f) {
    union { float f; uint32_t u; } c; c.f = f;
    uint32_t u = c.u + 0x7FFFu + ((c.u >> 16) & 1u);
    return (unsigned short)(u >> 16);
}

__device__ __forceinline__ uint4 pack8(float4v x, float4v y) {
    uint4 r;
    r.x = (uint32_t)f2bf(x[0]) | ((uint32_t)f2bf(x[1]) << 16);
    r.y = (uint32_t)f2bf(x[2]) | ((uint32_t)f2bf(x[3]) << 16);
    r.z = (uint32_t)f2bf(y[0]) | ((uint32_t)f2bf(y[1]) << 16);
    r.w = (uint32_t)f2bf(y[2]) | ((uint32_t)f2bf(y[3]) << 16);
    return r;
}

__device__ __forceinline__ void gload16(const unsigned short* g, unsigned short* l) {
    __builtin_amdgcn_global_load_lds(
        (const __attribute__((address_space(1))) unsigned int*)g,
        (__attribute__((address_space(3))) unsigned int*)l, 16, 0, 0);
}

// ---------------- pre-pass: bf16 tile images, XOR swizzle baked in ----------
// K image: Ks[row*128 + (cb ^ (row&7))*8 + e] = K[row][cb*8+e]   (row 0..63, cb 0..15)
// V image: Vt[dr*64  + (kb ^ (dr&7))*8 + e]  = V[kb*8+e][dr]     (dr 0..127, kb 0..7)
__global__ __launch_bounds__(256)
void prepass(const float* __restrict__ Kg, const float* __restrict__ Vg,
             unsigned short* __restrict__ Kb, unsigned short* __restrict__ Vb)
{
    const int t = threadIdx.x;
    const int tile = blockIdx.x, b = blockIdx.y;
    const size_t img = (size_t)(b * NT_ + tile) * IMG;

    // --- K image: coalesced-ish b128 reads, linear b128 writes ---
    {
        const float* src = Kg + ((size_t)b * S_ + tile * TN) * D_;
        unsigned short* dst = Kb + img;
        #pragma unroll
        for (int i = 0; i < 4; ++i) {
            int bid = i * 256 + t;            // 16B-block id 0..1023
            int row = bid >> 4, cbp = bid & 15;
            int cb  = cbp ^ (row & 7);
            const float* s = src + row * D_ + cb * 8;
            *(uint4*)(dst + (size_t)bid * 8) = pack8(*(const float4v*)s,
                                                     *(const float4v*)(s + 4));
        }
    }
    // --- V image: per-lane column gather (coalesced b32 reads), b128 writes ---
    {
        const float* src = Vg + ((size_t)b * S_ + tile * TN) * D_;
        unsigned short* dst = Vb + img;
        #pragma unroll
        for (int it = 0; it < 4; ++it) {
            int item = it * 256 + t;          // 0..1023
            int dr = item & 127, kb = item >> 7;
            const float* p = src + (size_t)(kb * 8) * D_ + dr;
            float v[8];
            #pragma unroll
            for (int i = 0; i < 8; ++i) v[i] = p[(size_t)i * D_];
            uint4 r;
            r.x = (uint32_t)f2bf(v[0]) | ((uint32_t)f2bf(v[1]) << 16);
            r.y = (uint32_t)f2bf(v[2]) | ((uint32_t)f2bf(v[3]) << 16);
            r.z = (uint32_t)f2bf(v[4]) | ((uint32_t)f2bf(v[5]) << 16);
            r.w = (uint32_t)f2bf(v[6]) | ((uint32_t)f2bf(v[7]) << 16);
            *(uint4*)(dst + dr * 64 + ((kb ^ (dr & 7)) << 3)) = r;
        }
    }
}

// ---------------- main flash-attention kernel --------------------------------
__global__ __launch_bounds__(256, 3)
void attn_fwd(const float* __restrict__ Qg,
              const unsigned short* __restrict__ Kb,
              const unsigned short* __restrict__ Vb,
              const int* __restrict__ VL,
              float* __restrict__ Og)
{
    __shared__ __align__(16) unsigned short Ks[TN * D_];   // 16 KB
    __shared__ __align__(16) unsigned short Vt[D_ * TN];   // 16 KB
    __shared__ __align__(16) unsigned short Ps[TM * TN];   // 16 KB, swizzled P
    __shared__ __align__(16) float lbuf[TM];

    const int t    = threadIdx.x;
    const int wave = t >> 6;
    const int lane = t & 63;
    const int l5   = lane & 31;   // MFMA m / n / C-col
    const int h    = lane >> 5;   // k-half
    const int swl  = l5 & 7;

    const int b  = blockIdx.y;
    const int q0 = blockIdx.x * TM;
    const int nvalid = VL[b];
    const int ntiles = (nvalid + TN - 1) / TN;

    const float scale = 0.08838834764831845f; // 1/sqrt(128), folded into Q

    // Q fragments: A[m = l5][k = ks*16 + h*8 + j], rows q0 + wave*32 + l5
    short8 qf[8];
    {
        const float* qp = Qg + ((size_t)b * S_ + (q0 + wave * 32 + l5)) * D_;
        #pragma unroll
        for (int ks = 0; ks < 8; ++ks) {
            float4v x = *(const float4v*)(qp + ks * 16 + h * 8);
            float4v y = *(const float4v*)(qp + ks * 16 + h * 8 + 4);
            #pragma unroll
            for (int j = 0; j < 4; ++j) { x[j] *= scale; y[j] *= scale; }
            union { uint4 u; short8 s; } cv; cv.u = pack8(x, y);
            qf[ks] = cv.s;
        }
    }

    const int mi = wave >> 1, ni = wave & 1;   // PV quadrant ownership
    f32x16 oacc[2][2];                         // [mtile][ntile], 64 rows x 64 dcols
    #pragma unroll
    for (int mt = 0; mt < 2; ++mt)
        #pragma unroll
        for (int nt = 0; nt < 2; ++nt)
            #pragma unroll
            for (int r = 0; r < 16; ++r) oacc[mt][nt][r] = 0.f;
    float lsum[2] = {0.f, 0.f};

    for (int tile = 0; tile < ntiles; ++tile) {
        const int n0 = tile * TN;
        __syncthreads();   // prior tile's Ks/Vt/Ps reads complete

        // ---- async-stage K and V tile images (pure DMA) ----
        {
            const unsigned short* kimg = Kb + (size_t)(b * NT_ + tile) * IMG;
            const unsigned short* vimg = Vb + (size_t)(b * NT_ + tile) * IMG;
            #pragma unroll
            for (int i = 0; i < 4; ++i) {
                int go = (i * 256 + t) * 8;
                int lo = (i * 256 + wave * 64) * 8;
                gload16(kimg + go, &Ks[lo]);
                gload16(vimg + go, &Vt[lo]);
            }
        }
        __syncthreads();

        // ---- S = Q K^T : 32 rows x 64 keys per wave, then exp + P write ----
        #pragma unroll
        for (int nt = 0; nt < 2; ++nt) {
            f32x16 sa;
            #pragma unroll
            for (int r = 0; r < 16; ++r) sa[r] = 0.f;
            #pragma unroll
            for (int ks = 0; ks < 8; ++ks) {
                short8 bf = *(const short8*)(&Ks[(nt * 32 + l5) * D_ + (((ks * 2 + h) ^ swl) << 3)]);
                sa = __builtin_amdgcn_mfma_f32_32x32x16_bf16(qf[ks], bf, sa, 0, 0, 0);
            }
            const bool ok = (n0 + nt * 32 + l5) < nvalid;
            const int cb  = nt * 4 + (l5 >> 3);
            #pragma unroll
            for (int r = 0; r < 16; ++r) {
                float p = ok ? __expf(sa[r]) : 0.0f;
                const int row = wave * 32 + (r & 3) + ((r >> 2) << 3) + (h << 2);
                Ps[row * TN + ((cb ^ (row & 7)) << 3) + swl] = f2bf(p);
            }
        }
        __syncthreads();   // P visible to all waves

        // ---- O quadrant += P V  (wave (mi,ni): rows mi*64.., dcols ni*64..) ----
        #pragma unroll
        for (int ks = 0; ks < 4; ++ks) {
            short8 pa[2];
            #pragma unroll
            for (int mt = 0; mt < 2; ++mt) {
                const int row = mi * 64 + mt * 32 + l5;
                pa[mt] = *(const short8*)(&Ps[row * TN + (((ks * 2 + h) ^ swl) << 3)]);
                union { short8 s; uint32_t u[4]; } pc; pc.s = pa[mt];
                #pragma unroll
                for (int q2 = 0; q2 < 4; ++q2)
                    lsum[mt] += __uint_as_float(pc.u[q2] << 16)
                              + __uint_as_float(pc.u[q2] & 0xFFFF0000u);
            }
            #pragma unroll
            for (int nt2 = 0; nt2 < 2; ++nt2) {
                const int dcol = ni * 64 + nt2 * 32 + l5;
                short8 vb = *(const short8*)(&Vt[dcol * TN + (((ks * 2 + h) ^ swl) << 3)]);
                oacc[0][nt2] = __builtin_amdgcn_mfma_f32_32x32x16_bf16(pa[0], vb, oacc[0][nt2], 0, 0, 0);
                oacc[1][nt2] = __builtin_amdgcn_mfma_f32_32x32x16_bf16(pa[1], vb, oacc[1][nt2], 0, 0, 0);
            }
        }
    }

    // ---- epilogue: l per row (combine k-halves), transpose via lbuf ----
    #pragma unroll
    for (int mt = 0; mt < 2; ++mt) {
        float l = lsum[mt] + __shfl_xor(lsum[mt], 32);
        lbuf[mi * 64 + mt * 32 + l5] = l;   // duplicate writers write identical values
    }
    __syncthreads();

    float* op = Og + ((size_t)b * S_ + q0) * D_;
    #pragma unroll
    for (int mt = 0; mt < 2; ++mt) {
        float4v il[4];
        #pragma unroll
        for (int rr = 0; rr < 4; ++rr) {
            float4v lv = *(const float4v*)(&lbuf[mi * 64 + mt * 32 + rr * 8 + h * 4]);
            #pragma unroll
            for (int j = 0; j < 4; ++j) il[rr][j] = 1.0f / lv[j];
        }
        #pragma unroll
        for (int nt2 = 0; nt2 < 2; ++nt2) {
            const int col = ni * 64 + nt2 * 32 + l5;
            #pragma unroll
            for (int r = 0; r < 16; ++r) {
                const int row = mi * 64 + mt * 32 + (r & 3) + ((r >> 2) << 3) + (h << 2);
                op[(size_t)row * D_ + col] = oacc[mt][nt2][r] * il[r >> 2][r & 3];
            }
        }
    }
}

extern "C" void kernel_launch(void* const* d_in, const int* in_sizes, int n_in,
                              void* d_out, int out_size, void* d_ws, size_t ws_size,
                              hipStream_t stream) {
    const float* Q = (const float*)d_in[0];
    const float* K = (const float*)d_in[1];
    const float* V = (const float*)d_in[2];
    const int*   L = (const int*)d_in[3];
    float*       O = (float*)d_out;

    unsigned short* Kb = (unsigned short*)d_ws;                 // 16.8 MB
    unsigned short* Vb = Kb + (size_t)B_ * S_ * D_;             // 16.8 MB

    dim3 grid(NT_, B_);
    prepass<<<grid, 256, 0, stream>>>(K, V, Kb, Vb);
    dim3 grid2(S_ / TM, B_);
    attn_fwd<<<grid2, 256, 0, stream>>>(Q, Kb, Vb, L, O);
}

// Round 5
// 264.537 us; speedup vs baseline: 1.1604x; 1.1604x over previous
//
#include <hip/hip_runtime.h>
#include <stdint.h>

typedef __attribute__((ext_vector_type(8))) short short8;   // 8 bf16 (4 VGPRs)
typedef __attribute__((ext_vector_type(4))) float float4v;

#define B_  16
#define S_  4096
#define D_  128
#define TM  64          // Q rows per block (4 waves x 16)
#define TN  64          // keys per tile
#define NT_ (S_ / TN)   // 64 key-tiles per batch
#define IMG 8192        // shorts per 64x128 tile image (16 KB)
#define CK  16          // key-tiles per chunk (1024 keys); chunks <= 4

// fp32 -> bf16 round-to-nearest-even
__device__ __forceinline__ unsigned short f2bf(float f) {
    union { float f; uint32_t u; } c; c.f = f;
    uint32_t u = c.u + 0x7FFFu + ((c.u >> 16) & 1u);
    return (unsigned short)(u >> 16);
}

__device__ __forceinline__ uint4 pack8(float4v x, float4v y) {
    uint4 r;
    r.x = (uint32_t)f2bf(x[0]) | ((uint32_t)f2bf(x[1]) << 16);
    r.y = (uint32_t)f2bf(x[2]) | ((uint32_t)f2bf(x[3]) << 16);
    r.z = (uint32_t)f2bf(y[0]) | ((uint32_t)f2bf(y[1]) << 16);
    r.w = (uint32_t)f2bf(y[2]) | ((uint32_t)f2bf(y[3]) << 16);
    return r;
}

__device__ __forceinline__ void gload16(const unsigned short* g, unsigned short* l) {
    __builtin_amdgcn_global_load_lds(
        (const __attribute__((address_space(1))) unsigned int*)g,
        (__attribute__((address_space(3))) unsigned int*)l, 16, 0, 0);
}

// ---------------- pre-pass: bf16 tile images, XOR swizzle baked in ----------
__global__ __launch_bounds__(256)
void prepass(const float* __restrict__ Kg, const float* __restrict__ Vg,
             unsigned short* __restrict__ Kb, unsigned short* __restrict__ Vb)
{
    const int t = threadIdx.x;
    const int tile = blockIdx.x, b = blockIdx.y;
    const size_t img = (size_t)(b * NT_ + tile) * IMG;

    {   // K image
        const float* src = Kg + ((size_t)b * S_ + tile * TN) * D_;
        unsigned short* dst = Kb + img;
        #pragma unroll
        for (int i = 0; i < 4; ++i) {
            int bid = i * 256 + t;
            int row = bid >> 4, cbp = bid & 15;
            int cb  = cbp ^ (row & 7);
            const float* s = src + row * D_ + cb * 8;
            *(uint4*)(dst + (size_t)bid * 8) = pack8(*(const float4v*)s,
                                                     *(const float4v*)(s + 4));
        }
    }
    {   // V image (transposed): Vt[dr*64 + (kb^(dr&7))*8 + e] = V[kb*8+e][dr]
        const float* src = Vg + ((size_t)b * S_ + tile * TN) * D_;
        unsigned short* dst = Vb + img;
        #pragma unroll
        for (int it = 0; it < 4; ++it) {
            int item = it * 256 + t;
            int dr = item & 127, kb = item >> 7;
            const float* p = src + (size_t)(kb * 8) * D_ + dr;
            float v[8];
            #pragma unroll
            for (int i = 0; i < 8; ++i) v[i] = p[(size_t)i * D_];
            uint4 r;
            r.x = (uint32_t)f2bf(v[0]) | ((uint32_t)f2bf(v[1]) << 16);
            r.y = (uint32_t)f2bf(v[2]) | ((uint32_t)f2bf(v[3]) << 16);
            r.z = (uint32_t)f2bf(v[4]) | ((uint32_t)f2bf(v[5]) << 16);
            r.w = (uint32_t)f2bf(v[6]) | ((uint32_t)f2bf(v[7]) << 16);
            *(uint4*)(dst + dr * 64 + ((kb ^ (dr & 7)) << 3)) = r;
        }
    }
}

// ---------------- split-K flash attention (round-3 core) ---------------------
__global__ __launch_bounds__(256, 4)
void attn_fwd(const float* __restrict__ Qg,
              const unsigned short* __restrict__ Kb,
              const unsigned short* __restrict__ Vb,
              const int* __restrict__ VL,
              float* __restrict__ Og,
              float* __restrict__ lbuf)
{
    __shared__ __align__(16) unsigned short Ks[TN * D_];     // 16 KB
    __shared__ __align__(16) unsigned short Vt[D_ * TN];     // 16 KB
    __shared__ __align__(16) unsigned short Ps[4 * 16 * 64]; // 8 KB

    const int b  = blockIdx.y;
    const int nvalid = VL[b];
    const int ntiles = (nvalid + TN - 1) / TN;
    const int ci = blockIdx.z;
    const int t0 = ci * CK;
    if (t0 >= ntiles) return;                    // empty chunk
    const int t1 = (t0 + CK < ntiles) ? (t0 + CK) : ntiles;
    const bool single = (ntiles <= CK);

    const int t    = threadIdx.x;
    const int wave = t >> 6;
    const int lane = t & 63;
    const int l16  = lane & 15;
    const int quad = lane >> 4;
    const int sw   = l16 & 7;
    const int q0   = blockIdx.x * TM;

    const float scale = 0.08838834764831845f; // 1/sqrt(128), folded into Q

    short8 qf[4];
    {
        const float* qp = Qg + ((size_t)b * S_ + (q0 + wave * 16 + l16)) * D_;
        #pragma unroll
        for (int ks = 0; ks < 4; ++ks) {
            float4v x = *(const float4v*)(qp + ks * 32 + quad * 8);
            float4v y = *(const float4v*)(qp + ks * 32 + quad * 8 + 4);
            #pragma unroll
            for (int j = 0; j < 4; ++j) { x[j] *= scale; y[j] *= scale; }
            union { uint4 u; short8 s; } cv; cv.u = pack8(x, y);
            qf[ks] = cv.s;
        }
    }

    float4v oacc[8];
    #pragma unroll
    for (int dt = 0; dt < 8; ++dt) oacc[dt] = (float4v){0.f, 0.f, 0.f, 0.f};
    float lsum[4] = {0.f, 0.f, 0.f, 0.f};

    unsigned short* Pw = Ps + wave * (16 * 64);

    for (int tile = t0; tile < t1; ++tile) {
        const int n0 = tile * TN;
        __syncthreads();

        {   // async-stage K and V tile images (pure DMA)
            const unsigned short* kimg = Kb + (size_t)(b * NT_ + tile) * IMG;
            const unsigned short* vimg = Vb + (size_t)(b * NT_ + tile) * IMG;
            #pragma unroll
            for (int i = 0; i < 4; ++i) {
                int go = (i * 256 + t) * 8;
                int lo = (i * 256 + wave * 64) * 8;
                gload16(kimg + go, &Ks[lo]);
                gload16(vimg + go, &Vt[lo]);
            }
        }
        __syncthreads();

        // S = Q K^T : 16 rows x 64 keys per wave
        float sv[4][4];
        #pragma unroll
        for (int nt = 0; nt < 4; ++nt) {
            float4v sa = (float4v){0.f, 0.f, 0.f, 0.f};
            #pragma unroll
            for (int ks = 0; ks < 4; ++ks) {
                short8 bf = *(const short8*)(&Ks[(nt * 16 + l16) * D_ + (((ks << 2) + quad) ^ sw) * 8]);
                sa = __builtin_amdgcn_mfma_f32_16x16x32_bf16(qf[ks], bf, sa, 0, 0, 0);
            }
            #pragma unroll
            for (int r = 0; r < 4; ++r) sv[nt][r] = sa[r];
        }

        // p = exp(s) (static max), accumulate l, write P swizzled
        const bool full = (n0 + TN) <= nvalid;
        #pragma unroll
        for (int nt = 0; nt < 4; ++nt) {
            const bool ok = full || (n0 + nt * 16 + l16) < nvalid;
            const int cb = nt * 2 + (l16 >> 3);
            #pragma unroll
            for (int r = 0; r < 4; ++r) {
                float p = ok ? __expf(sv[nt][r]) : 0.0f;
                lsum[r] += p;
                const int row = quad * 4 + r;
                Ps[wave * 1024 + row * 64 + ((cb ^ (row >> 1)) << 3) + sw] = f2bf(p);
            }
        }

        // O += P V
        short8 pf0 = *(const short8*)(&Pw[l16 * 64 + (((quad) ^ (l16 >> 1)) << 3)]);
        short8 pf1 = *(const short8*)(&Pw[l16 * 64 + (((4 + quad) ^ (l16 >> 1)) << 3)]);
        #pragma unroll
        for (int dt = 0; dt < 8; ++dt) {
            int col = dt * 16 + l16;
            int swc = 8 * (col & 7);
            short8 vf0 = *(const short8*)(&Vt[col * TN + ((quad * 8) ^ swc)]);
            short8 vf1 = *(const short8*)(&Vt[col * TN + ((32 + quad * 8) ^ swc)]);
            oacc[dt] = __builtin_amdgcn_mfma_f32_16x16x32_bf16(pf0, vf0, oacc[dt], 0, 0, 0);
            oacc[dt] = __builtin_amdgcn_mfma_f32_16x16x32_bf16(pf1, vf1, oacc[dt], 0, 0, 0);
        }
    }

    // epilogue
    float lred[4];
    #pragma unroll
    for (int r = 0; r < 4; ++r) {
        float s = lsum[r];
        #pragma unroll
        for (int off = 1; off < 16; off <<= 1)
            s += __shfl_xor(s, off);
        lred[r] = s;
    }

    float* op = Og + ((size_t)b * S_ + (q0 + wave * 16 + quad * 4)) * D_;
    if (single) {
        #pragma unroll
        for (int r = 0; r < 4; ++r) {
            float invl = 1.0f / lred[r];
            #pragma unroll
            for (int dt = 0; dt < 8; ++dt)
                op[r * D_ + dt * 16 + l16] = oacc[dt][r] * invl;
        }
    } else {
        #pragma unroll
        for (int r = 0; r < 4; ++r) {
            #pragma unroll
            for (int dt = 0; dt < 8; ++dt)
                atomicAdd(&op[r * D_ + dt * 16 + l16], oacc[dt][r]);
        }
        if (l16 == 0) {
            #pragma unroll
            for (int r = 0; r < 4; ++r)
                atomicAdd(&lbuf[b * S_ + q0 + wave * 16 + quad * 4 + r], lred[r]);
        }
    }
}

// ---------------- normalize multi-chunk rows ---------------------------------
__global__ __launch_bounds__(256)
void normalize(float* __restrict__ Og, const float* __restrict__ lbuf,
               const int* __restrict__ VL)
{
    const int f = blockIdx.x * 256 + threadIdx.x;   // float4 index
    const int b = f >> 17;                          // 131072 float4 per batch
    const int ntiles = (VL[b] + TN - 1) / TN;
    if (ntiles <= CK) return;                       // single-chunk: already final
    const int row = (f & 131071) >> 5;              // 32 float4 per row
    const float inv = 1.0f / lbuf[b * S_ + row];
    float4v* p = (float4v*)Og;
    float4v v = p[f];
    #pragma unroll
    for (int j = 0; j < 4; ++j) v[j] *= inv;
    p[f] = v;
}

extern "C" void kernel_launch(void* const* d_in, const int* in_sizes, int n_in,
                              void* d_out, int out_size, void* d_ws, size_t ws_size,
                              hipStream_t stream) {
    const float* Q = (const float*)d_in[0];
    const float* K = (const float*)d_in[1];
    const float* V = (const float*)d_in[2];
    const int*   L = (const int*)d_in[3];
    float*       O = (float*)d_out;

    unsigned short* Kb = (unsigned short*)d_ws;                 // 16.8 MB
    unsigned short* Vb = Kb + (size_t)B_ * S_ * D_;             // 16.8 MB
    float* lbuf = (float*)(Vb + (size_t)B_ * S_ * D_);          // 256 KB

    hipMemsetAsync(O, 0, (size_t)out_size * sizeof(float), stream);
    hipMemsetAsync(lbuf, 0, (size_t)B_ * S_ * sizeof(float), stream);

    dim3 grid(NT_, B_);
    prepass<<<grid, 256, 0, stream>>>(K, V, Kb, Vb);

    dim3 grid2(S_ / TM, B_, 4);
    attn_fwd<<<grid2, 256, 0, stream>>>(Q, Kb, Vb, L, O, lbuf);

    normalize<<<(out_size / 4 + 255) / 256, 256, 0, stream>>>(O, lbuf, L);
}